// Round 6
// baseline (116.968 us; speedup 1.0000x reference)
//
#include <hip/hip_runtime.h>
#include <math.h>

#define L 2048
#define LMASK (L - 1)
#define LB 512            // int4-blocks per row
#define LBMASK (LB - 1)
#define NCELL (L * L)
#define H 64

#define RED_BLOCKS 256
#define RED_THREADS 256
#define RED_ITERS (NCELL / 4 / (RED_BLOCKS * RED_THREADS))   // 16

// ---------------- Kernel 1: per-block partial sums (NO atomics) ----------------
__global__ void reduce_sum_kernel(const int* __restrict__ state,
                                  int* __restrict__ partials) {
    const int4* s4 = (const int4*)state;
    int tid = blockIdx.x * blockDim.x + threadIdx.x;
    int x = 0;
    #pragma unroll
    for (int k = 0; k < RED_ITERS; ++k) {
        int4 v = s4[tid + k * (RED_BLOCKS * RED_THREADS)];
        x += v.x + v.y + v.z + v.w;
    }
    #pragma unroll
    for (int off = 32; off > 0; off >>= 1)
        x += __shfl_down(x, off, 64);
    __shared__ int ls[4];
    if ((threadIdx.x & 63) == 0) ls[threadIdx.x >> 6] = x;
    __syncthreads();
    if (threadIdx.x == 0)
        partials[blockIdx.x] = ls[0] + ls[1] + ls[2] + ls[3];
}

// ---------------- Kernel 2: 12-combo MLP table ----------------
// table[b*4 + {0,1,2}] = {p0, p1, value} for combo b = s*6 + nc
__global__ void mlp_table_kernel(const float* __restrict__ W1,
                                 const float* __restrict__ b1,
                                 const float* __restrict__ W2,
                                 const float* __restrict__ b2,
                                 const float* __restrict__ Wa,
                                 const float* __restrict__ ba,
                                 const float* __restrict__ Wc,
                                 const float* __restrict__ bc,
                                 const int* __restrict__ partials,
                                 float* __restrict__ table) {
    __shared__ float h1[H];
    __shared__ float h2[H];
    int b = blockIdx.x;                     // 0..11
    int j = threadIdx.x;                    // 0..63

    // each block redundantly reduces the 256 partials (one wave, trivial)
    int sum = partials[j] + partials[j + 64] + partials[j + 128] + partials[j + 192];
    #pragma unroll
    for (int off = 32; off > 0; off >>= 1)
        sum += __shfl_xor(sum, off, 64);

    float f0 = (float)(b / 6);              // state
    float f1 = (float)(b % 6);              // neighbor_coop
    float f2 = (float)sum * (1.0f / (float)NCELL);  // global_coop

    float a = W1[0 * H + j] * f0 + W1[1 * H + j] * f1 + W1[2 * H + j] * f2 + b1[j];
    h1[j] = fmaxf(a, 0.0f);
    __syncthreads();

    float acc = b2[j];
    #pragma unroll
    for (int k = 0; k < H; ++k) acc += h1[k] * W2[k * H + j];
    h2[j] = fmaxf(acc, 0.0f);
    __syncthreads();

    if (j == 0) {
        float la = ba[0], lb = ba[1], v = bc[0];
        #pragma unroll
        for (int k = 0; k < H; ++k) {
            la += h2[k] * Wa[k * 2 + 0];
            lb += h2[k] * Wa[k * 2 + 1];
            v  += h2[k] * Wc[k];
        }
        float m = fmaxf(la, lb);
        float e0 = expf(la - m), e1 = expf(lb - m);
        float inv = 1.0f / (e0 + e1);
        table[b * 4 + 0] = e0 * inv;
        table[b * 4 + 1] = e1 * inv;
        table[b * 4 + 2] = v;
    }
}

// ---------------- Kernel 3: 2 rows x 4 cols per thread (vertical blocking) ----
// reward = 3*(n+s+e+w) + 2*(ne+nw+se+sw) + (nn+ss+ee+ww)   [center cancels]
// Vertical register blocking: 14 int4 loads for 8 cells (28 B/cell) vs the
// previous 11 int4 for 4 cells (44 B/cell) -> ~36% less issued load traffic,
// attacking the measured 2.05x FETCH over-fetch (34.5 MB vs 16.8 MB ideal).
__global__ void cell_kernel(const int* __restrict__ state,
                            const float* __restrict__ table,
                            float* __restrict__ out) {
    __shared__ float tbl[48];
    if (threadIdx.x < 48) tbl[threadIdx.x] = table[threadIdx.x];
    __syncthreads();

    int tid = blockIdx.x * blockDim.x + threadIdx.x;   // 0 .. NCELL/8-1
    int rp = tid >> 9;          // row-pair index, 0..1023
    int jb = tid & LBMASK;      // int4-block in row
    int i0 = rp * 2;            // even row
    int i1 = i0 + 1;
    int ra = (i0 - 2) & LMASK;  // i0-2
    int rb = (i0 - 1) & LMASK;  // i0-1
    int rc = i0;                // i0
    int rd = i1;                // i0+1
    int re = (i0 + 2) & LMASK;  // i0+2
    int rf = (i0 + 3) & LMASK;  // i0+3
    int jbm1 = (jb - 1) & LBMASK, jbp1 = (jb + 1) & LBMASK;

    const int4* s4 = (const int4*)state;
    // 4 middle rows need 3 blocks; 2 extreme rows need only the center block
    int4 b0 = s4[rb * LB + jbm1], b1_ = s4[rb * LB + jb], b2_ = s4[rb * LB + jbp1];
    int4 c0 = s4[rc * LB + jbm1], c1 = s4[rc * LB + jb], c2 = s4[rc * LB + jbp1];
    int4 d0 = s4[rd * LB + jbm1], d1 = s4[rd * LB + jb], d2 = s4[rd * LB + jbp1];
    int4 e0 = s4[re * LB + jbm1], e1 = s4[re * LB + jb], e2 = s4[re * LB + jbp1];
    int4 a1 = s4[ra * LB + jb];
    int4 f1 = s4[rf * LB + jb];

    int B[12] = {b0.x,b0.y,b0.z,b0.w, b1_.x,b1_.y,b1_.z,b1_.w, b2_.x,b2_.y,b2_.z,b2_.w};
    int C[12] = {c0.x,c0.y,c0.z,c0.w, c1.x,c1.y,c1.z,c1.w, c2.x,c2.y,c2.z,c2.w};
    int D[12] = {d0.x,d0.y,d0.z,d0.w, d1.x,d1.y,d1.z,d1.w, d2.x,d2.y,d2.z,d2.w};
    int E[12] = {e0.x,e0.y,e0.z,e0.w, e1.x,e1.y,e1.z,e1.w, e2.x,e2.y,e2.z,e2.w};
    int A4[4] = {a1.x,a1.y,a1.z,a1.w};
    int F4[4] = {f1.x,f1.y,f1.z,f1.w};

    float pr0[8], vv0[4], rw0[4];   // row i0
    float pr1[8], vv1[4], rw1[4];   // row i1
    #pragma unroll
    for (int t = 0; t < 4; ++t) {
        // ---- row i0: mid=C, north=B, south=D, nn=A, ss=E(mid) ----
        {
            int c  = C[4 + t], w  = C[3 + t], e  = C[5 + t];
            int ww = C[2 + t], ee = C[6 + t];
            int n  = B[4 + t], nw = B[3 + t], ne = B[5 + t];
            int s  = D[4 + t], sw = D[3 + t], se = D[5 + t];
            int nn = A4[t],    ss = E[4 + t];

            int axis1 = n + s + e + w;
            rw0[t] = (float)(3 * axis1 + 2 * (nw + ne + sw + se) + (nn + ss + ww + ee));
            int combo = c * 6 + (c + axis1);
            pr0[2 * t]     = tbl[combo * 4 + 0];
            pr0[2 * t + 1] = tbl[combo * 4 + 1];
            vv0[t]         = tbl[combo * 4 + 2];
        }
        // ---- row i1: mid=D, north=C, south=E, nn=B(mid), ss=F ----
        {
            int c  = D[4 + t], w  = D[3 + t], e  = D[5 + t];
            int ww = D[2 + t], ee = D[6 + t];
            int n  = C[4 + t], nw = C[3 + t], ne = C[5 + t];
            int s  = E[4 + t], sw = E[3 + t], se = E[5 + t];
            int nn = B[4 + t], ss = F4[t];

            int axis1 = n + s + e + w;
            rw1[t] = (float)(3 * axis1 + 2 * (nw + ne + sw + se) + (nn + ss + ww + ee));
            int combo = c * 6 + (c + axis1);
            pr1[2 * t]     = tbl[combo * 4 + 0];
            pr1[2 * t + 1] = tbl[combo * 4 + 1];
            vv1[t]         = tbl[combo * 4 + 2];
        }
    }

    float4* o4 = (float4*)out;
    int p0 = i0 * LB + jb;      // linear int4-block index of row i0 tile
    int p1 = i1 * LB + jb;
    o4[p0 * 2]     = make_float4(pr0[0], pr0[1], pr0[2], pr0[3]);
    o4[p0 * 2 + 1] = make_float4(pr0[4], pr0[5], pr0[6], pr0[7]);
    o4[p1 * 2]     = make_float4(pr1[0], pr1[1], pr1[2], pr1[3]);
    o4[p1 * 2 + 1] = make_float4(pr1[4], pr1[5], pr1[6], pr1[7]);
    float4* vplane = (float4*)(out + 2 * (size_t)NCELL);
    float4* rplane = (float4*)(out + 3 * (size_t)NCELL);
    vplane[p0] = make_float4(vv0[0], vv0[1], vv0[2], vv0[3]);
    vplane[p1] = make_float4(vv1[0], vv1[1], vv1[2], vv1[3]);
    rplane[p0] = make_float4(rw0[0], rw0[1], rw0[2], rw0[3]);
    rplane[p1] = make_float4(rw1[0], rw1[1], rw1[2], rw1[3]);
}

extern "C" void kernel_launch(void* const* d_in, const int* in_sizes, int n_in,
                              void* d_out, int out_size, void* d_ws, size_t ws_size,
                              hipStream_t stream) {
    const int*   state = (const int*)d_in[0];
    const float* W1 = (const float*)d_in[1];
    const float* b1 = (const float*)d_in[2];
    const float* W2 = (const float*)d_in[3];
    const float* b2 = (const float*)d_in[4];
    const float* Wa = (const float*)d_in[5];
    const float* ba = (const float*)d_in[6];
    const float* Wc = (const float*)d_in[7];
    const float* bc = (const float*)d_in[8];
    float* out = (float*)d_out;

    int*   partials = (int*)d_ws;                         // 256 ints
    float* table    = (float*)((char*)d_ws + 1024);       // 48 floats

    reduce_sum_kernel<<<RED_BLOCKS, RED_THREADS, 0, stream>>>(state, partials);
    mlp_table_kernel<<<12, 64, 0, stream>>>(W1, b1, W2, b2, Wa, ba, Wc, bc,
                                            partials, table);
    cell_kernel<<<NCELL / 8 / 256, 256, 0, stream>>>(state, table, out);
}

// Round 7
// 115.782 us; speedup vs baseline: 1.0102x; 1.0102x over previous
//
#include <hip/hip_runtime.h>
#include <math.h>

#define L 2048
#define LMASK (L - 1)
#define LB 512            // int4-blocks per row
#define LBMASK (LB - 1)
#define NCELL (L * L)
#define H 64

#define RED_BLOCKS 256
#define RED_THREADS 256
#define RED_ITERS (NCELL / 4 / (RED_BLOCKS * RED_THREADS))   // 16

// ---------------- Kernel 1: per-block partial sums (NO atomics) ----------------
__global__ void reduce_sum_kernel(const int* __restrict__ state,
                                  int* __restrict__ partials) {
    const int4* s4 = (const int4*)state;
    int tid = blockIdx.x * blockDim.x + threadIdx.x;
    int x = 0;
    #pragma unroll
    for (int k = 0; k < RED_ITERS; ++k) {
        int4 v = s4[tid + k * (RED_BLOCKS * RED_THREADS)];
        x += v.x + v.y + v.z + v.w;
    }
    #pragma unroll
    for (int off = 32; off > 0; off >>= 1)
        x += __shfl_down(x, off, 64);
    __shared__ int ls[4];
    if ((threadIdx.x & 63) == 0) ls[threadIdx.x >> 6] = x;
    __syncthreads();
    if (threadIdx.x == 0)
        partials[blockIdx.x] = ls[0] + ls[1] + ls[2] + ls[3];
}

// ---------------- Kernel 2: 12-combo MLP table ----------------
// table[b*4 + {0,1,2}] = {p0, p1, value} for combo b = s*6 + nc
__global__ void mlp_table_kernel(const float* __restrict__ W1,
                                 const float* __restrict__ b1,
                                 const float* __restrict__ W2,
                                 const float* __restrict__ b2,
                                 const float* __restrict__ Wa,
                                 const float* __restrict__ ba,
                                 const float* __restrict__ Wc,
                                 const float* __restrict__ bc,
                                 const int* __restrict__ partials,
                                 float* __restrict__ table) {
    __shared__ float h1[H];
    __shared__ float h2[H];
    int b = blockIdx.x;                     // 0..11
    int j = threadIdx.x;                    // 0..63

    // each block redundantly reduces the 256 partials (one wave, trivial)
    int sum = partials[j] + partials[j + 64] + partials[j + 128] + partials[j + 192];
    #pragma unroll
    for (int off = 32; off > 0; off >>= 1)
        sum += __shfl_xor(sum, off, 64);

    float f0 = (float)(b / 6);              // state
    float f1 = (float)(b % 6);              // neighbor_coop
    float f2 = (float)sum * (1.0f / (float)NCELL);  // global_coop

    float a = W1[0 * H + j] * f0 + W1[1 * H + j] * f1 + W1[2 * H + j] * f2 + b1[j];
    h1[j] = fmaxf(a, 0.0f);
    __syncthreads();

    float acc = b2[j];
    #pragma unroll
    for (int k = 0; k < H; ++k) acc += h1[k] * W2[k * H + j];
    h2[j] = fmaxf(acc, 0.0f);
    __syncthreads();

    if (j == 0) {
        float la = ba[0], lb = ba[1], v = bc[0];
        #pragma unroll
        for (int k = 0; k < H; ++k) {
            la += h2[k] * Wa[k * 2 + 0];
            lb += h2[k] * Wa[k * 2 + 1];
            v  += h2[k] * Wc[k];
        }
        float m = fmaxf(la, lb);
        float e0 = expf(la - m), e1 = expf(lb - m);
        float inv = 1.0f / (e0 + e1);
        table[b * 4 + 0] = e0 * inv;
        table[b * 4 + 1] = e1 * inv;
        table[b * 4 + 2] = v;
    }
}

// ---------------- Kernel 3: 4 cells/thread, int4 loads, float4 stores ----------
// reward = 3*(n+s+e+w) + 2*(ne+nw+se+sw) + (nn+ss+ee+ww)   [center cancels]
__global__ void cell_kernel(const int* __restrict__ state,
                            const float* __restrict__ table,
                            float* __restrict__ out) {
    __shared__ float tbl[48];
    if (threadIdx.x < 48) tbl[threadIdx.x] = table[threadIdx.x];
    __syncthreads();

    int tid = blockIdx.x * blockDim.x + threadIdx.x;   // 0 .. NCELL/4-1
    int i  = tid >> 9;          // row
    int jb = tid & LBMASK;      // int4-block in row
    int im1 = (i - 1) & LMASK, ip1 = (i + 1) & LMASK;
    int im2 = (i - 2) & LMASK, ip2 = (i + 2) & LMASK;
    int jbm1 = (jb - 1) & LBMASK, jbp1 = (jb + 1) & LBMASK;

    const int4* s4 = (const int4*)state;
    int4 m0 = s4[i   * LB + jbm1], m1 = s4[i   * LB + jb], m2 = s4[i   * LB + jbp1];
    int4 n0 = s4[im1 * LB + jbm1], n1 = s4[im1 * LB + jb], n2 = s4[im1 * LB + jbp1];
    int4 q0 = s4[ip1 * LB + jbm1], q1 = s4[ip1 * LB + jb], q2 = s4[ip1 * LB + jbp1];
    int4 uu4 = s4[im2 * LB + jb];
    int4 dd4 = s4[ip2 * LB + jb];

    int m [12] = {m0.x,m0.y,m0.z,m0.w, m1.x,m1.y,m1.z,m1.w, m2.x,m2.y,m2.z,m2.w};
    int nr[12] = {n0.x,n0.y,n0.z,n0.w, n1.x,n1.y,n1.z,n1.w, n2.x,n2.y,n2.z,n2.w};
    int sr[12] = {q0.x,q0.y,q0.z,q0.w, q1.x,q1.y,q1.z,q1.w, q2.x,q2.y,q2.z,q2.w};
    int ur[4]  = {uu4.x,uu4.y,uu4.z,uu4.w};
    int dr[4]  = {dd4.x,dd4.y,dd4.z,dd4.w};

    float pr[8], vv[4], rw[4];
    #pragma unroll
    for (int t = 0; t < 4; ++t) {
        int c  = m[4 + t],  w  = m[3 + t],  e  = m[5 + t];
        int ww = m[2 + t],  ee = m[6 + t];
        int n  = nr[4 + t], nw = nr[3 + t], ne = nr[5 + t];
        int s  = sr[4 + t], sw = sr[3 + t], se = sr[5 + t];
        int nn = ur[t],     ss = dr[t];

        int axis1 = n + s + e + w;
        rw[t] = (float)(3 * axis1 + 2 * (nw + ne + sw + se) + (nn + ss + ww + ee));

        int combo = c * 6 + (c + axis1);
        pr[2 * t]     = tbl[combo * 4 + 0];
        pr[2 * t + 1] = tbl[combo * 4 + 1];
        vv[t]         = tbl[combo * 4 + 2];
    }

    float4* o4 = (float4*)out;
    o4[tid * 2]     = make_float4(pr[0], pr[1], pr[2], pr[3]);
    o4[tid * 2 + 1] = make_float4(pr[4], pr[5], pr[6], pr[7]);
    ((float4*)(out + 2 * (size_t)NCELL))[tid] = make_float4(vv[0], vv[1], vv[2], vv[3]);
    ((float4*)(out + 3 * (size_t)NCELL))[tid] = make_float4(rw[0], rw[1], rw[2], rw[3]);
}

extern "C" void kernel_launch(void* const* d_in, const int* in_sizes, int n_in,
                              void* d_out, int out_size, void* d_ws, size_t ws_size,
                              hipStream_t stream) {
    const int*   state = (const int*)d_in[0];
    const float* W1 = (const float*)d_in[1];
    const float* b1 = (const float*)d_in[2];
    const float* W2 = (const float*)d_in[3];
    const float* b2 = (const float*)d_in[4];
    const float* Wa = (const float*)d_in[5];
    const float* ba = (const float*)d_in[6];
    const float* Wc = (const float*)d_in[7];
    const float* bc = (const float*)d_in[8];
    float* out = (float*)d_out;

    int*   partials = (int*)d_ws;                         // 256 ints
    float* table    = (float*)((char*)d_ws + 1024);       // 48 floats

    reduce_sum_kernel<<<RED_BLOCKS, RED_THREADS, 0, stream>>>(state, partials);
    mlp_table_kernel<<<12, 64, 0, stream>>>(W1, b1, W2, b2, Wa, ba, Wc, bc,
                                            partials, table);
    cell_kernel<<<NCELL / 4 / 256, 256, 0, stream>>>(state, table, out);
}